// Round 10
// baseline (113.300 us; speedup 1.0000x reference)
//
#include <hip/hip_runtime.h>

// GuidedFilterLayer: out = x*(1-eps) + eps*(2*smoothed - 1)
//   g        = luma((x+1)/2)
//   smoothed = boxblur15_zeropad(g + offset),  offset = mean(inputs)-mean(g)
// Linearity: boxblur_zeropad(g + c) = boxblur_zeropad(g) + c*cx(x)*cy(y)/225,
// so offset only enters the final combine. History: R3 removed 8192 contended
// atomics (232->128us); R6 rolling-sum vblur (->119); R8 fp16 tmp + rolling
// hblur + fused reduce (->112). Profile shows ~70us of dur_us is harness
// poison/restore traffic (268MB fills at 43us, 78% peak) — kernels ~40us vs
// ~25us ideal. R9/R10: K2 de-serialized — barrier-free per-wave offset reduce
// (float4 loads), init taps preloaded into registers BEFORE the reduce so the
// two latency chains overlap, nontemporal out stores via native clang vector
// type (R9 compile fix: builtin rejects HIP_vector_type float4).
// Shapes fixed by the reference: x [16,512,512,3] fp32 NHWC.

#define BATCH  16
#define HEIGHT 512
#define WIDTH  512
#define NPIX   (BATCH * HEIGHT * WIDTH)   // 4,194,304
#define RAD    7
#define KS     15
#define EPSV   0.01f

#define W_R 0.2989f
#define W_G 0.5870f
#define W_B 0.1140f

typedef _Float16 h4 __attribute__((ext_vector_type(4)));
typedef float    f4 __attribute__((ext_vector_type(4)));   // clang vector: ok for nontemporal builtin

// ---------------- K1: luma + rolling horizontal 15-tap + per-block partials -----------
// Block = 2 rows (1024 px), 256 threads; thread t owns pixels 4t..4t+3
// (= float4s 3t..3t+2, direct coalesced loads). Luma into aligned-pad LDS row
// ([8 pad][512][8 pad], 16B-aligned float4 write), one barrier, rolling
// 15-tap hblur (15 init + 6 update LDS reads per 4 outputs), fp16x4 tmp.
__global__ __launch_bounds__(256) void k_luma_hblur(const float* __restrict__ x,
                                                    h4* __restrict__ tmp,
                                                    float2* __restrict__ partials) {
    __shared__ float sl[2][528];            // [8 zero][512 luma][8 zero]
    __shared__ float redG[4], redI[4];
    int t  = threadIdx.x;
    int lr = t >> 7;                        // local row 0/1
    int tc = t & 127;                       // float4-column within row
    int c0 = tc << 2;                       // first pixel column

    if (t < 8) {                            // zero halos once (pre-barrier)
        sl[0][t] = 0.f; sl[1][t] = 0.f;
        sl[0][520 + t] = 0.f; sl[1][520 + t] = 0.f;
    }

    const float4* xv = (const float4*)x;
    size_t tb = (size_t)blockIdx.x * 768 + 3 * t;
    float4 A = xv[tb + 0];
    float4 B = xv[tb + 1];
    float4 C = xv[tb + 2];

    float r0 = (A.x + 1.f) * 0.5f, g0 = (A.y + 1.f) * 0.5f, b0 = (A.z + 1.f) * 0.5f;
    float r1 = (A.w + 1.f) * 0.5f, g1 = (B.x + 1.f) * 0.5f, b1 = (B.y + 1.f) * 0.5f;
    float r2 = (B.z + 1.f) * 0.5f, g2 = (B.w + 1.f) * 0.5f, b2 = (C.x + 1.f) * 0.5f;
    float r3 = (C.y + 1.f) * 0.5f, g3 = (C.z + 1.f) * 0.5f, b3 = (C.w + 1.f) * 0.5f;

    float l0 = W_R * r0 + W_G * g0 + W_B * b0;
    float l1 = W_R * r1 + W_G * g1 + W_B * b1;
    float l2 = W_R * r2 + W_G * g2 + W_B * b2;
    float l3 = W_R * r3 + W_G * g3 + W_B * b3;

    *(float4*)&sl[lr][8 + c0] = make_float4(l0, l1, l2, l3);   // aligned b128

    float sG = l0 + l1 + l2 + l3;
    float sI = r0 + g0 + b0 + r1 + g1 + b1 + r2 + g2 + b2 + r3 + g3 + b3;
#pragma unroll
    for (int off = 32; off > 0; off >>= 1) {
        sG += __shfl_down(sG, off, 64);
        sI += __shfl_down(sI, off, 64);
    }
    int lane = t & 63, wave = t >> 6;
    if (lane == 0) { redG[wave] = sG; redI[wave] = sI; }
    __syncthreads();                        // covers sl + redG/redI

    if (t == 0)
        partials[blockIdx.x] = make_float2(redG[0] + redG[1] + redG[2] + redG[3],
                                           redI[0] + redI[1] + redI[2] + redI[3]);

    // rolling hblur: window for col c = slots [c+1 .. c+15]
    const float* row = sl[lr];
    float s = 0.f;
#pragma unroll
    for (int d = 1; d <= 15; d++) s += row[c0 + d];
    float o0 = s;
    s += row[c0 + 16] - row[c0 + 1];  float o1 = s;
    s += row[c0 + 17] - row[c0 + 2];  float o2 = s;
    s += row[c0 + 18] - row[c0 + 3];  float o3 = s;

    h4 hv; hv.x = (_Float16)o0; hv.y = (_Float16)o1; hv.z = (_Float16)o2; hv.w = (_Float16)o3;
    tmp[(size_t)(blockIdx.x * 2 + lr) * 128 + tc] = hv;   // 1/225 folded into K2
}

// ---------------- K2: rolling vblur + fused combine (barrier-free) --------------------
// Block = 128 threads (thread t owns float4 column t) x TROWS=8 rows of one
// image; 1024 blocks = 2 waves/SIMD. Init taps are preloaded into registers,
// THEN each wave independently reduces the 2048 partials (float4 loads, no
// LDS/barrier) while taps are in flight; rolling vertical sum = 2 fp16x4 tap
// loads/row; combine pure registers; nontemporal out stores.
#define TROWS 8
__global__ __launch_bounds__(128) void k_vblur_combine(const h4* __restrict__ tmp,
                                                       const float* __restrict__ x,
                                                       float* __restrict__ out,
                                                       const float2* __restrict__ partials) {
    int t    = threadIdx.x;
    int band = blockIdx.x & (HEIGHT / TROWS - 1);
    int b    = blockIdx.x >> 6;             // 512/8 = 64 bands per image
    int y0   = band * TROWS;

    const h4* tv = tmp + (size_t)b * HEIGHT * 128 + t;
    const h4  hz = (h4)(_Float16)0.f;

    // ---- issue all 15 init-tap loads first (rows y0-7 .. y0+7, clipped) ----
#define TAP(j) h4 w##j = (y0 - RAD + (j) >= 0) ? tv[(size_t)(y0 - RAD + (j)) * 128] : hz
    TAP(0);  TAP(1);  TAP(2);  TAP(3);  TAP(4);  TAP(5);  TAP(6);  TAP(7);
    TAP(8);  TAP(9);  TAP(10); TAP(11); TAP(12); TAP(13); TAP(14);
#undef TAP

    // ---- offset reduce, per-wave (all lanes see same result; no barrier) ----
    const float4* pv = (const float4*)partials;     // 1024 float4 = 2048 float2
    int lane = t & 63;
    float sG = 0.f, sI = 0.f;
#pragma unroll
    for (int i = 0; i < 16; i++) {
        float4 v = pv[lane + (i << 6)];
        sG += v.x + v.z;
        sI += v.y + v.w;
    }
#pragma unroll
    for (int off = 32; off > 0; off >>= 1) {
        sG += __shfl_xor(sG, off, 64);      // butterfly: every lane gets the total
        sI += __shfl_xor(sI, off, 64);
    }
    float offset = sI * (1.f / (3.f * (float)NPIX)) - sG * (1.f / (float)NPIX);

    const float nrm   = 1.f / (float)(KS * KS);
    const float scale = 1.f - EPSV;
    int col = t << 2;
    float c0 = (float)(min(col + 0, RAD) + 1 + min(WIDTH - 1 - col, RAD));
    float c1 = (float)(min(col + 1, RAD) + 1 + min(WIDTH - 2 - col, RAD));
    float c2 = (float)(min(col + 2, RAD) + 1 + min(WIDTH - 3 - col, RAD));
    float c3 = (float)(min(col + 3, RAD) + 1 + min(WIDTH - 4 - col, RAD));

    // ---- accumulate the preloaded window ----
    float s0 = 0.f, s1 = 0.f, s2 = 0.f, s3 = 0.f;
#define ACC(j) s0 += (float)w##j.x; s1 += (float)w##j.y; s2 += (float)w##j.z; s3 += (float)w##j.w
    ACC(0);  ACC(1);  ACC(2);  ACC(3);  ACC(4);  ACC(5);  ACC(6);  ACC(7);
    ACC(8);  ACC(9);  ACC(10); ACC(11); ACC(12); ACC(13); ACC(14);
#undef ACC

    const float4* xv = (const float4*)x + (size_t)b * HEIGHT * 384;
    f4*           ov = (f4*)out         + (size_t)b * HEIGHT * 384;

#pragma unroll
    for (int i = 0; i < TROWS; ++i) {
        int y = y0 + i;
        float cy = (float)(min(y, RAD) + 1 + min(HEIGHT - 1 - y, RAD));
        float k  = offset * cy;
        float a0 = EPSV * (2.f * (s0 + k * c0) * nrm - 1.f);
        float a1 = EPSV * (2.f * (s1 + k * c1) * nrm - 1.f);
        float a2 = EPSV * (2.f * (s2 + k * c2) * nrm - 1.f);
        float a3 = EPSV * (2.f * (s3 + k * c3) * nrm - 1.f);

        size_t rb = (size_t)y * 384 + 3 * t;
        float4 x0 = xv[rb + 0];
        float4 x1 = xv[rb + 1];
        float4 x2 = xv[rb + 2];
        f4 o0, o1, o2;
        o0.x = x0.x * scale + a0; o0.y = x0.y * scale + a0;
        o0.z = x0.z * scale + a0; o0.w = x0.w * scale + a1;
        o1.x = x1.x * scale + a1; o1.y = x1.y * scale + a1;
        o1.z = x1.z * scale + a2; o1.w = x1.w * scale + a2;
        o2.x = x2.x * scale + a2; o2.y = x2.y * scale + a3;
        o2.z = x2.z * scale + a3; o2.w = x2.w * scale + a3;
        __builtin_nontemporal_store(o0, &ov[rb + 0]);
        __builtin_nontemporal_store(o1, &ov[rb + 1]);
        __builtin_nontemporal_store(o2, &ov[rb + 2]);

        if (y + RAD + 1 < HEIGHT) {         // wave-uniform
            h4 v = tv[(size_t)(y + RAD + 1) * 128];
            s0 += (float)v.x; s1 += (float)v.y; s2 += (float)v.z; s3 += (float)v.w;
        }
        if (y - RAD >= 0) {
            h4 v = tv[(size_t)(y - RAD) * 128];
            s0 -= (float)v.x; s1 -= (float)v.y; s2 -= (float)v.z; s3 -= (float)v.w;
        }
    }
}

extern "C" void kernel_launch(void* const* d_in, const int* in_sizes, int n_in,
                              void* d_out, int out_size, void* d_ws, size_t ws_size,
                              hipStream_t stream) {
    const float* x   = (const float*)d_in[0];
    float*       out = (float*)d_out;

    // ws layout: [0, 16K): partials (2048 float2) | [32K, 32K+8.4M): tmp fp16
    float2* partials = (float2*)d_ws;
    h4*     tmp      = (h4*)((char*)d_ws + 32768);

    k_luma_hblur<<<BATCH * HEIGHT / 2, 256, 0, stream>>>(x, tmp, partials);
    k_vblur_combine<<<BATCH * (HEIGHT / TROWS), 128, 0, stream>>>(tmp, x, out, partials);
}